// Round 1
// baseline (33.582 us; speedup 1.0000x reference)
//
#include <hip/hip_runtime.h>

#define TT 2048
#define BB 4096
#define DROP_ROWS 11
#define PERIOD 24
#define BLOCK 256
#define HALF 12

__global__ __launch_bounds__(BLOCK) void seasonal_decomp_kernel(
    const float* __restrict__ x, float* __restrict__ out) {
  __shared__ float sx[TT];       // raw row
  __shared__ float sd[TT];       // detrended row
  __shared__ float pp[PERIOD][8];
  __shared__ float pmean[PERIOD];

  const int row = blockIdx.x + DROP_ROWS;

  // ---- coalesced float4 load of the row into LDS ----
  {
    const float4* rx = (const float4*)(x + (size_t)row * TT);
    float4* s4 = (float4*)sx;
    #pragma unroll
    for (int i = 0; i < TT / 4 / BLOCK; ++i) {
      s4[threadIdx.x + i * BLOCK] = rx[threadIdx.x + i * BLOCK];
    }
  }
  __syncthreads();

  // ---- trend (clipped centered moving average) + detrended ----
  float tr[TT / BLOCK];  // 8 per thread, static indexing (stays in VGPRs)
  #pragma unroll
  for (int i = 0; i < TT / BLOCK; ++i) {
    int t = threadIdx.x + i * BLOCK;
    int s = t - HALF; if (s < 0) s = 0;
    int e = t + HALF + 1; if (e > TT) e = TT;
    float sum = 0.f;
    for (int k = s; k < e; ++k) sum += sx[k];
    tr[i] = sum / (float)(e - s);
    sd[t] = sx[t] - tr[i];
  }
  __syncthreads();

  // ---- per-phase partial sums (deterministic order, no atomics) ----
  if (threadIdx.x < PERIOD * 8) {
    int p = threadIdx.x >> 3;
    int j = threadIdx.x & 7;
    int cnt = (p < 8) ? 86 : 85;   // 2048 = 85*24 + 8
    float s = 0.f;
    for (int m = j; m < cnt; m += 8) s += sd[p + PERIOD * m];
    pp[p][j] = s;
  }
  __syncthreads();
  if (threadIdx.x < PERIOD) {
    float s = 0.f;
    #pragma unroll
    for (int j = 0; j < 8; ++j) s += pp[threadIdx.x][j];
    pmean[threadIdx.x] = s / ((threadIdx.x < 8) ? 86.f : 85.f);
  }
  __syncthreads();

  // ---- epilogue: packed {trend, seasonal, residual} store ----
  float* orow = out + (size_t)blockIdx.x * TT * 3;
  #pragma unroll
  for (int i = 0; i < TT / BLOCK; ++i) {
    int t = threadIdx.x + i * BLOCK;
    float sea = pmean[t % PERIOD];
    float res = sd[t] - sea;
    float3 v = make_float3(tr[i], sea, res);
    *(float3*)(orow + (size_t)t * 3) = v;
  }
}

extern "C" void kernel_launch(void* const* d_in, const int* in_sizes, int n_in,
                              void* d_out, int out_size, void* d_ws, size_t ws_size,
                              hipStream_t stream) {
  const float* x = (const float*)d_in[0];
  float* out = (float*)d_out;
  seasonal_decomp_kernel<<<BB - DROP_ROWS, BLOCK, 0, stream>>>(x, out);
}

// Round 2
// 27.364 us; speedup vs baseline: 1.2272x; 1.2272x over previous
//
#include <hip/hip_runtime.h>

#define TT 2048
#define BB 4096
#define DROP_ROWS 11
#define PERIOD 24
#define BLOCK 256
#define HALF 12
#define WAVES (BLOCK / 64)

__global__ __launch_bounds__(BLOCK) void seasonal_decomp_kernel(
    const float* __restrict__ x, float* __restrict__ out) {
  // buf overlays three logically-disjoint-in-time arrays:
  //   sd   = buf[0..2047]      (detrended row; live: trend -> phase sums)
  //   cs   = buf[2048..4096]   (exclusive cumsum, 2049 floats; live: scan -> trend)
  //   sout = buf[0..6143]      (packed output row; live: epilogue only)
  __shared__ float buf[6144];
  __shared__ float wt0[WAVES], wt1[WAVES];
  __shared__ float pp[PERIOD][8];
  __shared__ float pmean[PERIOD];
  float* const sd = buf;
  float* const cs = buf + 2048;
  float* const sout = buf;

  const int tid = threadIdx.x;
  const int lane = tid & 63;
  const int wave = tid >> 6;
  const int row = blockIdx.x + DROP_ROWS;

  // ---- coalesced load: two float4 per thread, kept in registers ----
  const float4* rx = (const float4*)(x + (size_t)row * TT);
  float4 v0 = rx[tid];          // elements [4*tid .. 4*tid+3]
  float4 v1 = rx[tid + 256];    // elements [1024+4*tid .. 1024+4*tid+3]

  // ---- hierarchical exclusive cumsum ----
  float s0 = v0.x + v0.y + v0.z + v0.w;
  float s1 = v1.x + v1.y + v1.z + v1.w;
  float i0 = s0, i1 = s1;       // wave-inclusive scans of chunk sums
  #pragma unroll
  for (int off = 1; off < 64; off <<= 1) {
    float t0 = __shfl_up(i0, off, 64);
    float t1 = __shfl_up(i1, off, 64);
    if (lane >= off) { i0 += t0; i1 += t1; }
  }
  if (lane == 63) { wt0[wave] = i0; wt1[wave] = i1; }
  __syncthreads();
  float W0 = 0.f, W1 = 0.f, H = 0.f;
  #pragma unroll
  for (int w = 0; w < WAVES; ++w) {
    float a = wt0[w], b = wt1[w];
    H += a;
    if (w < wave) { W0 += a; W1 += b; }
  }
  const float P0 = W0 + (i0 - s0);            // cs[4*tid]
  const float P1 = H + W1 + (i1 - s1);        // cs[1024 + 4*tid]

  float4 c0, c1;
  c0.x = P0; c0.y = P0 + v0.x; c0.z = c0.y + v0.y; c0.w = c0.z + v0.z;
  c1.x = P1; c1.y = P1 + v1.x; c1.z = c1.y + v1.y; c1.w = c1.z + v1.z;
  ((float4*)cs)[tid] = c0;                    // ds_write_b128, natural pattern
  ((float4*)cs)[tid + 256] = c1;
  if (tid == 255) cs[TT] = P1 + s1;           // grand total
  __syncthreads();

  // ---- trend + detrended (4 stride-1 LDS reads per element) ----
  float tr[8], sdr[8];
  #pragma unroll
  for (int j = 0; j < 8; ++j) {
    int t = tid + 256 * j;
    int s = t - HALF; if (s < 0) s = 0;
    int e = t + HALF + 1; if (e > TT) e = TT;
    float wsum = cs[e] - cs[s];
    float xt = cs[t + 1] - cs[t];
    tr[j] = wsum / (float)(e - s);
    sdr[j] = xt - tr[j];
    sd[t] = sdr[j];
  }
  __syncthreads();

  // ---- per-phase partial sums (deterministic, no atomics) ----
  if (tid < PERIOD * 8) {
    int p = tid >> 3;
    int j = tid & 7;
    int cnt = (p < 8) ? 86 : 85;              // 2048 = 85*24 + 8
    float s = 0.f;
    for (int m = j; m < cnt; m += 8) s += sd[p + PERIOD * m];
    pp[p][j] = s;
  }
  __syncthreads();
  if (tid < PERIOD) {
    float s = 0.f;
    #pragma unroll
    for (int j = 0; j < 8; ++j) s += pp[tid][j];
    pmean[tid] = s / ((tid < 8) ? 86.f : 85.f);
  }
  __syncthreads();

  // ---- epilogue: pack row in LDS (stride-3 writes = 2-way, free), ----
  // ---- then fully-coalesced float4 stores                         ----
  #pragma unroll
  for (int j = 0; j < 8; ++j) {
    int t = tid + 256 * j;
    float sea = pmean[t % PERIOD];
    sout[3 * t]     = tr[j];
    sout[3 * t + 1] = sea;
    sout[3 * t + 2] = sdr[j] - sea;
  }
  __syncthreads();
  float4* orow = (float4*)(out + (size_t)blockIdx.x * (TT * 3));
  const float4* so4 = (const float4*)sout;
  #pragma unroll
  for (int j = 0; j < 6; ++j) orow[tid + 256 * j] = so4[tid + 256 * j];
}

extern "C" void kernel_launch(void* const* d_in, const int* in_sizes, int n_in,
                              void* d_out, int out_size, void* d_ws, size_t ws_size,
                              hipStream_t stream) {
  const float* x = (const float*)d_in[0];
  float* out = (float*)d_out;
  seasonal_decomp_kernel<<<BB - DROP_ROWS, BLOCK, 0, stream>>>(x, out);
}